// Round 7
// baseline (1065.865 us; speedup 1.0000x reference)
//
#include <hip/hip_runtime.h>
#include <hip/hip_bf16.h>

// ===========================================================================
// EEGRCformer forward on MI355X. ALL tensors float32.
// R7: replace cluster_kernel (263us, 2.9% occupancy) with
//   featsT transpose (coalesced) -> dist_kernel (2048 blocks, no LDS,
//   coalesced j-reads + broadcast i-reads) -> fps_kernel (light).
// Everything else = R6 (feat v6 via x-transpose, transposed weights).
// ===========================================================================

#define N_SIG   7936
#define FDIM    504
#define DM      128
#define CHUNK   3968          // signals per transpose/feat chunk
#define X2STR   (CHUNK*2)

// ws offsets (floats)
#define OFF_FEATS  0                      // 3,999,744
#define OFF_FEATST 4000000                // 4,064,256  (128*504*64)
#define OFF_X2     0                      // 7,936,000 (dead before norm)
#define OFF_PSD    8100000                // 1,999,872
#define OFF_DSQ    8100000                // 492,032 (alias psd; psd dead)
#define OFF_PF     8600000                // 1,015,808
#define OFF_BASIS  10100000               // 22,000
#define OFF_PROJT  10122000               // 64,512
#define OFF_WQKVT  10186512               // 147,456
#define OFF_WOT    10333968               // 49,152
#define OFF_W1T    10383120               // 98,304
#define OFF_W2T    10481424               // 98,304
#define OFF_GSUM   10579728               // 15
#define OFF_GCNT   10579743               // 5
#define OFF_ASSIGN 10579748               // 64 ints

// block reduce of (a,b) over 128 threads (2 waves); scr must be >=4 floats
static __device__ __forceinline__ void bred2(float& a, float& b, volatile float* scr, int tid){
    #pragma unroll
    for (int off = 32; off > 0; off >>= 1){
        a += __shfl_down(a, off, 64);
        b += __shfl_down(b, off, 64);
    }
    if ((tid & 63) == 0){ scr[tid>>6] = a; scr[2 + (tid>>6)] = b; }
    __syncthreads();
    a = scr[0] + scr[1];
    b = scr[2] + scr[3];
    __syncthreads();
}

// ---------------------------------------------------------------------------
// Kernel P: precompute basis + transpose weights + zero gsums/gcnt.
// ---------------------------------------------------------------------------
__global__ __launch_bounds__(256) void prep_kernel(
        const float* __restrict__ proj_w, const float* __restrict__ Wqkv,
        const float* __restrict__ Wo, const float* __restrict__ W1,
        const float* __restrict__ W2, float* __restrict__ ws)
{
    int idx = blockIdx.x*256 + threadIdx.x;
    if (idx < 22000){
        int cc = idx / 5500, r = idx % 5500;
        int step = r / 44, q = r % 44;
        int bin = q >> 2, c = q & 3;
        int k = 1 + cc*11 + bin;
        int n = 2*step + (c & 1);
        const float TPO = 0.025132741228718345f;  // 2*pi/250
        int m = (k*n) % 250;
        float th = (float)m * TPO;
        float hw = 0.5f*(1.f - cosf((float)n * TPO));
        float v = (c < 2) ? hw*cosf(th) : hw*sinf(th);
        ws[OFF_BASIS + idx] = v;
        return;
    }
    idx -= 22000;
    if (idx < 64512){                         // projT[k][d] = proj_w[d][k]
        int k = idx / 128, d = idx % 128;
        ws[OFF_PROJT + idx] = proj_w[d*504 + k];
        return;
    }
    idx -= 64512;
    if (idx < 147456){                        // WqkvT[L][k][r]
        int L = idx / 49152, rem = idx % 49152;
        int k = rem / 384, r = rem % 384;
        ws[OFF_WQKVT + idx] = Wqkv[((size_t)L*384 + r)*128 + k];
        return;
    }
    idx -= 147456;
    if (idx < 49152){                         // WoT[L][k][d]
        int L = idx / 16384, rem = idx % 16384;
        int k = rem / 128, d = rem % 128;
        ws[OFF_WOT + idx] = Wo[((size_t)L*128 + d)*128 + k];
        return;
    }
    idx -= 49152;
    if (idx < 98304){                         // W1T[L][k][r]
        int L = idx / 32768, rem = idx % 32768;
        int k = rem / 256, r = rem % 256;
        ws[OFF_W1T + idx] = W1[((size_t)L*256 + r)*128 + k];
        return;
    }
    idx -= 98304;
    if (idx < 98304){                         // W2T[L][k(256)][d]
        int L = idx / 32768, rem = idx % 32768;
        int k = rem / 128, d = rem % 128;
        ws[OFF_W2T + idx] = W2[((size_t)L*128 + d)*256 + k];
        return;
    }
    idx -= 98304;
    if (idx < 20) ws[OFF_GSUM + idx] = 0.f;
}

// ---------------------------------------------------------------------------
// Kernel T: transpose one chunk of x -> x2[pair][sig*2]. grid (62,40) x 256.
// ---------------------------------------------------------------------------
__global__ __launch_bounds__(256) void transpose_kernel(
        const float* __restrict__ x, float* __restrict__ x2c, int sigBase)
{
    __shared__ float xs[64*53];
    const int tid  = threadIdx.x;
    const int sig0 = blockIdx.x * 64;
    const int n0   = blockIdx.y * 50;

    for (int idx = tid; idx < 3200; idx += 256){
        int r = idx / 50, c = idx - r*50;
        xs[r*53 + c] = x[(size_t)(sigBase + sig0 + r)*2000 + n0 + c];
    }
    __syncthreads();
    for (int idx = tid; idx < 1600; idx += 256){
        int c2 = idx >> 6, lane = idx & 63;
        float2 v = make_float2(xs[lane*53 + 2*c2], xs[lane*53 + 2*c2 + 1]);
        *(float2*)(x2c + (size_t)(n0/2 + c2)*X2STR + (sig0 + lane)*2) = v;
    }
}

// ---------------------------------------------------------------------------
// Kernel A: DFT -> band psd means -> psd scratch. grid (62,9) x 256.
// ---------------------------------------------------------------------------
__global__ __launch_bounds__(256) void feat_kernel(
        const float* __restrict__ x2c, const float* __restrict__ basisP,
        float* __restrict__ psd, int sigBase)
{
    constexpr int band_of[46] = {
        -1, 0,0,0, 1,1,1,1, 2,2,2,2, 3,3,3,3, 4,4,4,4,
        5,5,5,5,5,5,5,5,5,5,
        6,6,6,6,6,6,6,6,6,6,6,6,6,6,6};
    constexpr float invcnt[7] = {1.f/3.f, 0.25f, 0.25f, 0.25f, 0.25f, 0.1f, 1.f/15.f};

    const int tid  = threadIdx.x;
    const int wave = tid >> 6, lane = tid & 63;
    const int win  = blockIdx.y * 4 + wave;
    const int ls   = blockIdx.x * 64 + lane;
    const int gsig = sigBase + ls;

    float bands[7] = {0,0,0,0,0,0,0};
    const float2* xbase = (const float2*)x2c + (size_t)(25*win)*CHUNK + ls;

    #pragma unroll
    for (int cc = 0; cc < 4; ++cc){
        const float* bp = basisP + cc*5500;
        float ar[11], ai[11];
        #pragma unroll
        for (int k = 0; k < 11; ++k){ ar[k] = 0.f; ai[k] = 0.f; }

        const float2* xp = xbase;
        for (int step = 0; step < 125; ++step){
            float2 xv = *xp; xp += CHUNK;
            const float* bs = bp + step*44;
            #pragma unroll
            for (int k = 0; k < 11; ++k){
                float4 b = *(const float4*)(bs + k*4);
                ar[k] = fmaf(xv.x, b.x, fmaf(xv.y, b.y, ar[k]));
                ai[k] = fmaf(xv.x, b.z, fmaf(xv.y, b.w, ai[k]));
            }
        }
        #pragma unroll
        for (int k = 0; k < 11; ++k){
            float p = fmaf(ar[k], ar[k], ai[k]*ai[k]) * (1.0f/250.0f);
            bands[band_of[1 + cc*11 + k]] += p;
        }
    }
    float* ob = psd + (size_t)gsig*252 + win*7;
    #pragma unroll
    for (int b = 0; b < 7; ++b) ob[b] = bands[b] * invcnt[b];
}

// ---------------------------------------------------------------------------
// Kernel N: per-signal z-norm of psd + DE -> feats. 1984 x 256 (wave=sig).
// ---------------------------------------------------------------------------
__global__ __launch_bounds__(256) void norm_kernel(
        const float* __restrict__ psd, float* __restrict__ feats)
{
    const int tid = threadIdx.x;
    const int wave = tid >> 6, lane = tid & 63;
    const int sig = blockIdx.x*4 + wave;

    float pv[4], dv[4];
    float s1p=0,s2p=0,s1d=0,s2d=0;
    #pragma unroll
    for (int i = 0; i < 4; ++i){
        int e = lane + i*64;
        if (e < 252){
            float p = psd[(size_t)sig*252 + e];
            float d = 0.5f * logf(17.079468445347134f*p + 1e-9f);
            pv[i] = p; dv[i] = d;
            s1p += p; s2p += p*p; s1d += d; s2d += d*d;
        }
    }
    #pragma unroll
    for (int off = 32; off > 0; off >>= 1){
        s1p += __shfl_down(s1p, off, 64); s2p += __shfl_down(s2p, off, 64);
        s1d += __shfl_down(s1d, off, 64); s2d += __shfl_down(s2d, off, 64);
    }
    s1p = __shfl(s1p, 0, 64); s2p = __shfl(s2p, 0, 64);
    s1d = __shfl(s1d, 0, 64); s2d = __shfl(s2d, 0, 64);
    float mp = s1p / 252.f;
    float sp = sqrtf(fmaxf((s2p - 252.f*mp*mp) / 251.f, 0.f)) + 1e-9f;
    float md = s1d / 252.f;
    float sd = sqrtf(fmaxf((s2d - 252.f*md*md) / 251.f, 0.f)) + 1e-9f;

    float* ob = feats + (size_t)sig * FDIM;
    #pragma unroll
    for (int i = 0; i < 4; ++i){
        int e = lane + i*64;
        if (e < 252){
            int w = e / 7, bi = e - w*7;
            ob[w*14 + bi]     = (pv[i] - mp) / sp;
            ob[w*14 + 7 + bi] = (dv[i] - md) / sd;
        }
    }
}

// ---------------------------------------------------------------------------
// Kernel FT: feats[b*62+c][k] -> featsT[b][k][64(c)]. grid (128,8) x 256.
// k-tile = 63. LDS 62 x 64. Coalesced in and out.
// ---------------------------------------------------------------------------
__global__ __launch_bounds__(256) void featsT_kernel(
        const float* __restrict__ feats, float* __restrict__ featsT)
{
    __shared__ float t[62*64];
    const int tid = threadIdx.x;
    const int b   = blockIdx.x;
    const int k0  = blockIdx.y * 63;

    for (int idx = tid; idx < 62*63; idx += 256){
        int c = idx / 63, kk = idx - c*63;
        t[c*64 + kk] = feats[((size_t)b*62 + c)*FDIM + k0 + kk];
    }
    __syncthreads();
    for (int idx = tid; idx < 63*62; idx += 256){
        int kk = idx / 62, c = idx - kk*62;
        featsT[((size_t)b*504 + k0 + kk)*64 + c] = t[c*64 + kk];
    }
}

// ---------------------------------------------------------------------------
// Kernel DD: D^2[b][i][j]. grid (128,16) x 256. i wave-uniform broadcast,
// j = lane (coalesced). No LDS -> high occupancy.
// ---------------------------------------------------------------------------
__global__ __launch_bounds__(256) void dist_kernel(
        const float* __restrict__ featsT, float* __restrict__ Dsq)
{
    const int b    = blockIdx.x;
    const int wv   = threadIdx.x >> 6, lane = threadIdx.x & 63;
    const int i    = blockIdx.y * 4 + wv;
    const float* base = featsT + (size_t)b*504*64;

    float acc = 0.f;
    #pragma unroll 4
    for (int k = 0; k < 504; ++k){
        float fi = base[(size_t)k*64 + i];
        float fj = base[(size_t)k*64 + lane];
        float d = fi - fj;
        acc = fmaf(d, d, acc);
    }
    if (i < 62 && lane < 62)
        Dsq[(size_t)b*3844 + i*62 + lane] = acc;
}

// ---------------------------------------------------------------------------
// Kernel B2: Dm=sqrt(Dsq) -> FPS(5) -> temp assign -> atomics. 128 x 256.
// ---------------------------------------------------------------------------
__global__ __launch_bounds__(256) void fps_kernel(
        const float* __restrict__ Dsq, const float* __restrict__ pos_emb,
        float* __restrict__ gsums, float* __restrict__ gcnt)
{
    __shared__ float Dm[62*62];
    __shared__ float mdv[62];
    __shared__ float rsv[62];
    __shared__ int   seli[5];
    __shared__ float ccen[5][3];

    const int tid = threadIdx.x;
    const int b   = blockIdx.x;

    for (int e = tid; e < 3844; e += 256)
        Dm[e] = sqrtf(Dsq[(size_t)b*3844 + e]);
    __syncthreads();

    if (tid < 62){ float s = 0.f; for (int j = 0; j < 62; ++j) s += Dm[tid*62 + j]; rsv[tid] = s; }
    __syncthreads();
    if (tid == 0){
        int bi = 0; float bv = rsv[0];
        for (int i = 1; i < 62; ++i) if (rsv[i] > bv){ bv = rsv[i]; bi = i; }
        seli[0] = bi;
    }
    __syncthreads();
    if (tid < 62) mdv[tid] = Dm[seli[0]*62 + tid];
    __syncthreads();
    for (int it = 1; it < 5; ++it){
        if (tid == 0){
            int bi = 0; float bv = mdv[0];
            for (int i = 1; i < 62; ++i) if (mdv[i] > bv){ bv = mdv[i]; bi = i; }
            seli[it] = bi;
        }
        __syncthreads();
        if (tid < 62) mdv[tid] = fminf(mdv[tid], Dm[seli[it]*62 + tid]);
        __syncthreads();
    }
    if (tid < 5){
        int c0 = seli[tid];
        #pragma unroll
        for (int j = 0; j < 3; ++j) ccen[tid][j] = pos_emb[((size_t)b*62 + c0)*3 + j];
    }
    __syncthreads();
    if (tid < 62){
        float px = pos_emb[((size_t)b*62 + tid)*3 + 0];
        float py = pos_emb[((size_t)b*62 + tid)*3 + 1];
        float pz = pos_emb[((size_t)b*62 + tid)*3 + 2];
        int best = 0; float bd = 3.4e38f;
        #pragma unroll
        for (int t = 0; t < 5; ++t){
            float dx = px - ccen[t][0], dy = py - ccen[t][1], dz = pz - ccen[t][2];
            float d2 = dx*dx + dy*dy + dz*dz;
            if (d2 < bd){ bd = d2; best = t; }
        }
        atomicAdd(&gsums[best*3 + 0], px);
        atomicAdd(&gsums[best*3 + 1], py);
        atomicAdd(&gsums[best*3 + 2], pz);
        atomicAdd(&gcnt[best], 1.f);
    }
}

// ---------------------------------------------------------------------------
// Kernel C: pos FPS centers, center update, stable order + greedy assignment.
// ---------------------------------------------------------------------------
__global__ __launch_bounds__(64) void finalize_kernel(
        const float* __restrict__ pos_emb, const float* __restrict__ gsums,
        const float* __restrict__ gcnt, int* __restrict__ assign_out)
{
    __shared__ float P[62*3];
    __shared__ float Dp[62*62];
    __shared__ float rsv[62];
    __shared__ float mdv[62];
    __shared__ int   seli[5];
    __shared__ float cenS[5][3];
    __shared__ int   ordS[62][5];
    const int tid = threadIdx.x;

    if (tid < 62){
        #pragma unroll
        for (int j = 0; j < 3; ++j) P[tid*3 + j] = pos_emb[(size_t)tid*3 + j];
    }
    __syncthreads();
    if (tid < 62){
        float xi = P[tid*3], yi = P[tid*3+1], zi = P[tid*3+2];
        float s = 0.f;
        for (int j = 0; j < 62; ++j){
            float dx = xi - P[j*3], dy = yi - P[j*3+1], dz = zi - P[j*3+2];
            float d = sqrtf(dx*dx + dy*dy + dz*dz);
            Dp[tid*62 + j] = d; s += d;
        }
        rsv[tid] = s;
    }
    __syncthreads();
    if (tid == 0){
        int bi = 0; float bv = rsv[0];
        for (int i = 1; i < 62; ++i) if (rsv[i] > bv){ bv = rsv[i]; bi = i; }
        seli[0] = bi;
        for (int i = 0; i < 62; ++i) mdv[i] = Dp[bi*62 + i];
        for (int it = 1; it < 5; ++it){
            int fi = 0; float fv = mdv[0];
            for (int i = 1; i < 62; ++i) if (mdv[i] > fv){ fv = mdv[i]; fi = i; }
            seli[it] = fi;
            for (int i = 0; i < 62; ++i) mdv[i] = fminf(mdv[i], Dp[fi*62 + i]);
        }
        float cen[5][3], avg[5][3];
        for (int t = 0; t < 5; ++t)
            for (int j = 0; j < 3; ++j) cen[t][j] = P[seli[t]*3 + j];
        for (int t = 0; t < 5; ++t){
            float c = gcnt[t];
            for (int j = 0; j < 3; ++j)
                avg[t][j] = (c > 0.f) ? gsums[t*3 + j] / fmaxf(c, 1.f) : 0.f;
        }
        for (int i = 0; i < 5; ++i){
            int m = 0; float bv2 = 3.4e38f;
            for (int j = 0; j < 5; ++j){
                float dx = cen[i][0]-avg[j][0], dy = cen[i][1]-avg[j][1], dz = cen[i][2]-avg[j][2];
                float d2 = dx*dx + dy*dy + dz*dz;
                if (d2 < bv2){ bv2 = d2; m = j; }
            }
            for (int j = 0; j < 3; ++j) cenS[i][j] = 0.8f*cen[i][j] + 0.2f*avg[m][j];
        }
    }
    __syncthreads();
    if (tid < 62){
        float dd[5];
        #pragma unroll
        for (int t = 0; t < 5; ++t){
            float dx = P[tid*3]-cenS[t][0], dy = P[tid*3+1]-cenS[t][1], dz = P[tid*3+2]-cenS[t][2];
            dd[t] = sqrtf(dx*dx + dy*dy + dz*dz);
        }
        bool tk[5] = {false,false,false,false,false};
        #pragma unroll
        for (int s = 0; s < 5; ++s){
            int best = -1;
            #pragma unroll
            for (int t = 0; t < 5; ++t)
                if (!tk[t] && (best < 0 || dd[t] < dd[best])) best = t;
            tk[best] = true; ordS[tid][s] = best;
        }
    }
    __syncthreads();
    if (tid == 0){
        const int sizesA[5] = {13,13,12,12,12};
        int counts[5] = {0,0,0,0,0};
        for (int i = 0; i < 62; ++i){
            int cl = ordS[i][0];
            #pragma unroll
            for (int s = 0; s < 5; ++s){
                int t = ordS[i][s];
                if (counts[t] < sizesA[t]){ cl = t; break; }
            }
            counts[cl]++;
            assign_out[i] = cl;
        }
    }
}

// ---------------------------------------------------------------------------
// Kernel D: pf = relu(LN(feats @ W.T + b)) with TRANSPOSED weights.
// ---------------------------------------------------------------------------
__global__ __launch_bounds__(128) void proj_kernel(
        const float* __restrict__ feats, const float* __restrict__ projT,
        const float* __restrict__ proj_b, const float* __restrict__ lng,
        const float* __restrict__ lnb, float* __restrict__ pf)
{
    __shared__ float fs[8*FDIM];
    __shared__ float scr[4];
    const int tid = threadIdx.x;
    const int row0 = blockIdx.x * 8;

    for (int i = tid; i < 8*FDIM; i += 128)
        fs[i] = feats[(size_t)row0*FDIM + i];
    __syncthreads();

    float acc[8];
    const float bias = proj_b[tid];
    #pragma unroll
    for (int g = 0; g < 8; ++g) acc[g] = bias;

    #pragma unroll 4
    for (int k = 0; k < FDIM; ++k){
        float w = projT[k*128 + tid];
        #pragma unroll
        for (int g = 0; g < 8; ++g)
            acc[g] = fmaf(fs[g*FDIM + k], w, acc[g]);
    }
    const float gl = lng[tid], bl = lnb[tid];
    #pragma unroll
    for (int g = 0; g < 8; ++g){
        float s1 = acc[g], s2 = acc[g]*acc[g];
        bred2(s1, s2, scr, tid);
        float m = s1 * (1.f/128.f);
        float var = fmaxf(s2 * (1.f/128.f) - m*m, 0.f);
        float y = (acc[g] - m) / sqrtf(var + 1e-5f);
        y = y*gl + bl;
        pf[(size_t)(row0 + g)*DM + tid] = fmaxf(y, 0.f);
    }
}

// ---------------------------------------------------------------------------
// Kernel F: token pooling + 3-layer transformer, TRANSPOSED weights.
// ---------------------------------------------------------------------------
__global__ __launch_bounds__(128) void former_kernel(
        const float* __restrict__ pf, const int* __restrict__ assign,
        const float* __restrict__ pos_enc,
        const float* __restrict__ WqkvT, const float* __restrict__ bqkv,
        const float* __restrict__ WoT,   const float* __restrict__ bo,
        const float* __restrict__ W1T,   const float* __restrict__ b1,
        const float* __restrict__ W2T,   const float* __restrict__ b2,
        const float* __restrict__ ln1g, const float* __restrict__ ln1b,
        const float* __restrict__ ln2g, const float* __restrict__ ln2b,
        float* __restrict__ out)
{
    __shared__ float h[5*128];
    __shared__ float qkvL[5*384];
    __shared__ float attL[100];
    __shared__ float oL[5*128];
    __shared__ float hidL[5*256];
    __shared__ int   asg[62];
    __shared__ float scr[4];

    const int b = blockIdx.x;
    const int d = threadIdx.x;

    if (d < 62) asg[d] = assign[d];
    __syncthreads();

    {   // token pooling
        float a0=0,a1=0,a2=0,a3=0,a4=0;
        const float* pfb = pf + (size_t)b*62*DM + d;
        for (int c = 0; c < 62; ++c){
            float v = pfb[(size_t)c*DM];
            int a = asg[c];
            a0 += (a==0)?v:0.f; a1 += (a==1)?v:0.f; a2 += (a==2)?v:0.f;
            a3 += (a==3)?v:0.f; a4 += (a==4)?v:0.f;
        }
        h[0*128+d] = a0/13.f + pos_enc[0*128+d];
        h[1*128+d] = a1/13.f + pos_enc[1*128+d];
        h[2*128+d] = a2/12.f + pos_enc[2*128+d];
        h[3*128+d] = a3/12.f + pos_enc[3*128+d];
        h[4*128+d] = a4/12.f + pos_enc[4*128+d];
    }
    __syncthreads();

    for (int L = 0; L < 3; ++L){
        float acc[3][5];
        #pragma unroll
        for (int rr = 0; rr < 3; ++rr){
            float bb = bqkv[L*384 + rr*128 + d];
            #pragma unroll
            for (int t = 0; t < 5; ++t) acc[rr][t] = bb;
        }
        {
            const float* WT = WqkvT + (size_t)L*128*384;
            #pragma unroll 4
            for (int k = 0; k < 128; ++k){
                float h0 = h[0*128+k], h1 = h[1*128+k], h2 = h[2*128+k];
                float h3 = h[3*128+k], h4 = h[4*128+k];
                #pragma unroll
                for (int rr = 0; rr < 3; ++rr){
                    float w = WT[(size_t)k*384 + rr*128 + d];
                    acc[rr][0] = fmaf(h0, w, acc[rr][0]);
                    acc[rr][1] = fmaf(h1, w, acc[rr][1]);
                    acc[rr][2] = fmaf(h2, w, acc[rr][2]);
                    acc[rr][3] = fmaf(h3, w, acc[rr][3]);
                    acc[rr][4] = fmaf(h4, w, acc[rr][4]);
                }
            }
        }
        #pragma unroll
        for (int rr = 0; rr < 3; ++rr)
            #pragma unroll
            for (int t = 0; t < 5; ++t)
                qkvL[t*384 + rr*128 + d] = acc[rr][t];
        __syncthreads();

        if (d < 100){
            int hh = d/25, rem = d - hh*25, tq = rem/5, tk = rem - (rem/5)*5;
            const float* qq = &qkvL[tq*384 + hh*32];
            const float* kk = &qkvL[tk*384 + 128 + hh*32];
            float s = 0.f;
            #pragma unroll
            for (int j = 0; j < 32; ++j) s = fmaf(qq[j], kk[j], s);
            attL[d] = s * 0.17677669529663687f;
        }
        __syncthreads();
        if (d < 20){
            int hh = d/5, tq = d - hh*5;
            float* row = &attL[hh*25 + tq*5];
            float mx = row[0];
            #pragma unroll
            for (int j = 1; j < 5; ++j) mx = fmaxf(mx, row[j]);
            float sm = 0.f;
            #pragma unroll
            for (int j = 0; j < 5; ++j){ float e = expf(row[j]-mx); row[j] = e; sm += e; }
            float inv = 1.f/sm;
            #pragma unroll
            for (int j = 0; j < 5; ++j) row[j] *= inv;
        }
        __syncthreads();

        {
            int hh = d >> 5;
            #pragma unroll
            for (int t = 0; t < 5; ++t){
                float s = 0.f;
                #pragma unroll
                for (int tk = 0; tk < 5; ++tk)
                    s = fmaf(attL[hh*25 + t*5 + tk], qkvL[tk*384 + 256 + d], s);
                oL[t*128 + d] = s;
            }
        }
        __syncthreads();

        float val[5];
        {
            float bv = bo[L*128 + d];
            #pragma unroll
            for (int t = 0; t < 5; ++t) val[t] = bv;
            const float* WT = WoT + (size_t)L*128*128;
            #pragma unroll 4
            for (int k = 0; k < 128; ++k){
                float w = WT[(size_t)k*128 + d];
                #pragma unroll
                for (int t = 0; t < 5; ++t)
                    val[t] = fmaf(oL[t*128 + k], w, val[t]);
            }
            #pragma unroll
            for (int t = 0; t < 5; ++t) val[t] += h[t*128 + d];
        }
        {
            float ng = ln1g[L*128 + d], nb = ln1b[L*128 + d];
            #pragma unroll
            for (int t = 0; t < 5; ++t){
                float s1 = val[t], s2 = val[t]*val[t];
                bred2(s1, s2, scr, d);
                float m = s1*(1.f/128.f);
                float var = fmaxf(s2*(1.f/128.f) - m*m, 0.f);
                float y = (val[t] - m) / sqrtf(var + 1e-5f);
                h[t*128 + d] = y*ng + nb;
            }
        }
        __syncthreads();

        {
            float f1[2][5];
            #pragma unroll
            for (int rr = 0; rr < 2; ++rr){
                float bb = b1[L*256 + rr*128 + d];
                #pragma unroll
                for (int t = 0; t < 5; ++t) f1[rr][t] = bb;
            }
            const float* WT = W1T + (size_t)L*128*256;
            #pragma unroll 4
            for (int k = 0; k < 128; ++k){
                float h0 = h[0*128+k], h1 = h[1*128+k], h2 = h[2*128+k];
                float h3 = h[3*128+k], h4 = h[4*128+k];
                #pragma unroll
                for (int rr = 0; rr < 2; ++rr){
                    float w = WT[(size_t)k*256 + rr*128 + d];
                    f1[rr][0] = fmaf(h0, w, f1[rr][0]);
                    f1[rr][1] = fmaf(h1, w, f1[rr][1]);
                    f1[rr][2] = fmaf(h2, w, f1[rr][2]);
                    f1[rr][3] = fmaf(h3, w, f1[rr][3]);
                    f1[rr][4] = fmaf(h4, w, f1[rr][4]);
                }
            }
            #pragma unroll
            for (int rr = 0; rr < 2; ++rr)
                #pragma unroll
                for (int t = 0; t < 5; ++t)
                    hidL[t*256 + rr*128 + d] = fmaxf(f1[rr][t], 0.f);
        }
        __syncthreads();

        {
            float v2[5];
            float bv = b2[L*128 + d];
            #pragma unroll
            for (int t = 0; t < 5; ++t) v2[t] = bv;
            const float* WT = W2T + (size_t)L*256*128;
            #pragma unroll 4
            for (int k = 0; k < 256; ++k){
                float w = WT[(size_t)k*128 + d];
                #pragma unroll
                for (int t = 0; t < 5; ++t)
                    v2[t] = fmaf(hidL[t*256 + k], w, v2[t]);
            }
            #pragma unroll
            for (int t = 0; t < 5; ++t) v2[t] += h[t*128 + d];
            float ng = ln2g[L*128 + d], nb = ln2b[L*128 + d];
            #pragma unroll
            for (int t = 0; t < 5; ++t){
                float s1 = v2[t], s2 = v2[t]*v2[t];
                bred2(s1, s2, scr, d);
                float m = s1*(1.f/128.f);
                float var = fmaxf(s2*(1.f/128.f) - m*m, 0.f);
                float y = (v2[t] - m) / sqrtf(var + 1e-5f);
                h[t*128 + d] = y*ng + nb;
            }
        }
        __syncthreads();
    }

    #pragma unroll
    for (int t = 0; t < 5; ++t)
        out[((size_t)b*5 + t)*128 + d] = h[t*128 + d];
}

// ---------------------------------------------------------------------------
extern "C" void kernel_launch(void* const* d_in, const int* in_sizes, int n_in,
                              void* d_out, int out_size, void* d_ws, size_t ws_size,
                              hipStream_t stream)
{
    const float* x        = (const float*)d_in[0];
    const float* pos_emb  = (const float*)d_in[1];
    const float* proj_w   = (const float*)d_in[2];
    const float* proj_b   = (const float*)d_in[3];
    const float* proj_lng = (const float*)d_in[4];
    const float* proj_lnb = (const float*)d_in[5];
    const float* pos_enc  = (const float*)d_in[6];
    const float* Wqkv     = (const float*)d_in[7];
    const float* bqkv     = (const float*)d_in[8];
    const float* Wo       = (const float*)d_in[9];
    const float* bo       = (const float*)d_in[10];
    const float* W1       = (const float*)d_in[11];
    const float* b1       = (const float*)d_in[12];
    const float* W2       = (const float*)d_in[13];
    const float* b2       = (const float*)d_in[14];
    const float* ln1g     = (const float*)d_in[15];
    const float* ln1b     = (const float*)d_in[16];
    const float* ln2g     = (const float*)d_in[17];
    const float* ln2b     = (const float*)d_in[18];

    float* ws     = (float*)d_ws;
    float* x2c    = ws + OFF_X2;
    float* feats  = ws + OFF_FEATS;
    float* featsT = ws + OFF_FEATST;
    float* psd    = ws + OFF_PSD;
    float* Dsq    = ws + OFF_DSQ;
    float* pf     = ws + OFF_PF;
    float* basisP = ws + OFF_BASIS;
    float* projT  = ws + OFF_PROJT;
    float* WqkvT  = ws + OFF_WQKVT;
    float* WoT    = ws + OFF_WOT;
    float* W1T    = ws + OFF_W1T;
    float* W2T    = ws + OFF_W2T;
    float* gsums  = ws + OFF_GSUM;
    float* gcnt   = ws + OFF_GCNT;
    int*   assign = (int*)(ws + OFF_ASSIGN);

    float* out = (float*)d_out;

    prep_kernel<<<1875, 256, 0, stream>>>(proj_w, Wqkv, Wo, W1, W2, ws);
    transpose_kernel<<<dim3(62,40), 256, 0, stream>>>(x, x2c, 0);
    feat_kernel<<<dim3(62,9), 256, 0, stream>>>(x2c, basisP, psd, 0);
    transpose_kernel<<<dim3(62,40), 256, 0, stream>>>(x, x2c, CHUNK);
    feat_kernel<<<dim3(62,9), 256, 0, stream>>>(x2c, basisP, psd, CHUNK);
    norm_kernel<<<1984, 256, 0, stream>>>(psd, feats);
    featsT_kernel<<<dim3(128,8), 256, 0, stream>>>(feats, featsT);
    dist_kernel<<<dim3(128,16), 256, 0, stream>>>(featsT, Dsq);
    fps_kernel<<<128, 256, 0, stream>>>(Dsq, pos_emb, gsums, gcnt);
    finalize_kernel<<<1, 64, 0, stream>>>(pos_emb, gsums, gcnt, assign);
    proj_kernel<<<992, 128, 0, stream>>>(feats, projT, proj_b, proj_lng, proj_lnb, pf);
    former_kernel<<<128, 128, 0, stream>>>(pf, assign, pos_enc,
        WqkvT, bqkv, WoT, bo, W1T, b1, W2T, b2, ln1g, ln1b, ln2g, ln2b, out);
}

// Round 8
// 1027.214 us; speedup vs baseline: 1.0376x; 1.0376x over previous
//
#include <hip/hip_runtime.h>
#include <hip/hip_bf16.h>

// ===========================================================================
// EEGRCformer forward on MI355X. ALL tensors float32.
// R8: (1) feat merged into ONE dispatch over all 7936 sigs (occupancy 22->~50%)
//     when ws_size allows (73.4MB); fallback = R7 2-chunk path (branch on
//     ws_size, constant per session -> graph-safe).
//     (2) dist v2: 4 i-rows/wave -> 4x less fj traffic.
//     (3) feat step loop unroll x2.
// ===========================================================================

#define N_SIG   7936
#define FDIM    504
#define DM      128

// block reduce of (a,b) over 128 threads (2 waves); scr must be >=4 floats
static __device__ __forceinline__ void bred2(float& a, float& b, volatile float* scr, int tid){
    #pragma unroll
    for (int off = 32; off > 0; off >>= 1){
        a += __shfl_down(a, off, 64);
        b += __shfl_down(b, off, 64);
    }
    if ((tid & 63) == 0){ scr[tid>>6] = a; scr[2 + (tid>>6)] = b; }
    __syncthreads();
    a = scr[0] + scr[1];
    b = scr[2] + scr[3];
    __syncthreads();
}

// ---------------------------------------------------------------------------
// Kernel P: precompute basis + transpose weights + zero gsums/gcnt.
// Explicit destination pointers (layout chosen by launcher).
// ---------------------------------------------------------------------------
__global__ __launch_bounds__(256) void prep_kernel(
        const float* __restrict__ proj_w, const float* __restrict__ Wqkv,
        const float* __restrict__ Wo, const float* __restrict__ W1,
        const float* __restrict__ W2,
        float* __restrict__ basis, float* __restrict__ projT,
        float* __restrict__ WqkvT, float* __restrict__ WoT,
        float* __restrict__ W1T, float* __restrict__ W2T,
        float* __restrict__ gz)
{
    int idx = blockIdx.x*256 + threadIdx.x;
    if (idx < 22000){
        int cc = idx / 5500, r = idx % 5500;
        int step = r / 44, q = r % 44;
        int bin = q >> 2, c = q & 3;
        int k = 1 + cc*11 + bin;
        int n = 2*step + (c & 1);
        const float TPO = 0.025132741228718345f;  // 2*pi/250
        int m = (k*n) % 250;
        float th = (float)m * TPO;
        float hw = 0.5f*(1.f - cosf((float)n * TPO));
        float v = (c < 2) ? hw*cosf(th) : hw*sinf(th);
        basis[idx] = v;
        return;
    }
    idx -= 22000;
    if (idx < 64512){ int k = idx / 128, d = idx % 128; projT[idx] = proj_w[d*504 + k]; return; }
    idx -= 64512;
    if (idx < 147456){
        int L = idx / 49152, rem = idx % 49152;
        int k = rem / 384, r = rem % 384;
        WqkvT[idx] = Wqkv[((size_t)L*384 + r)*128 + k];
        return;
    }
    idx -= 147456;
    if (idx < 49152){
        int L = idx / 16384, rem = idx % 16384;
        int k = rem / 128, d = rem % 128;
        WoT[idx] = Wo[((size_t)L*128 + d)*128 + k];
        return;
    }
    idx -= 49152;
    if (idx < 98304){
        int L = idx / 32768, rem = idx % 32768;
        int k = rem / 256, r = rem % 256;
        W1T[idx] = W1[((size_t)L*256 + r)*128 + k];
        return;
    }
    idx -= 98304;
    if (idx < 98304){
        int L = idx / 32768, rem = idx % 32768;
        int k = rem / 128, d = rem % 128;
        W2T[idx] = W2[((size_t)L*128 + d)*256 + k];
        return;
    }
    idx -= 98304;
    if (idx < 20) gz[idx] = 0.f;
}

// ---------------------------------------------------------------------------
// Kernel T: transpose chunk of x -> x2[pair][sig*2]. grid (W/64, 40) x 256.
// chunkW = signals in this x2 buffer (stride).
// ---------------------------------------------------------------------------
__global__ __launch_bounds__(256) void transpose_kernel(
        const float* __restrict__ x, float* __restrict__ x2c,
        int sigBase, int chunkW)
{
    __shared__ float xs[64*53];
    const int tid  = threadIdx.x;
    const int sig0 = blockIdx.x * 64;
    const int n0   = blockIdx.y * 50;

    for (int idx = tid; idx < 3200; idx += 256){
        int r = idx / 50, c = idx - r*50;
        xs[r*53 + c] = x[(size_t)(sigBase + sig0 + r)*2000 + n0 + c];
    }
    __syncthreads();
    for (int idx = tid; idx < 1600; idx += 256){
        int c2 = idx >> 6, lane = idx & 63;
        float2 v = make_float2(xs[lane*53 + 2*c2], xs[lane*53 + 2*c2 + 1]);
        *(float2*)(x2c + (size_t)(n0/2 + c2)*(size_t)chunkW*2 + (sig0 + lane)*2) = v;
    }
}

// ---------------------------------------------------------------------------
// Kernel A: DFT -> band psd means -> psd scratch. grid (W/64, 9) x 256.
// wave = one window of 64 signals; lanes = signals (coalesced x), basis
// wave-uniform. No LDS.
// ---------------------------------------------------------------------------
__global__ __launch_bounds__(256) void feat_kernel(
        const float* __restrict__ x2c, const float* __restrict__ basisP,
        float* __restrict__ psd, int sigBase, int chunkW)
{
    constexpr int band_of[46] = {
        -1, 0,0,0, 1,1,1,1, 2,2,2,2, 3,3,3,3, 4,4,4,4,
        5,5,5,5,5,5,5,5,5,5,
        6,6,6,6,6,6,6,6,6,6,6,6,6,6,6};
    constexpr float invcnt[7] = {1.f/3.f, 0.25f, 0.25f, 0.25f, 0.25f, 0.1f, 1.f/15.f};

    const int tid  = threadIdx.x;
    const int wave = tid >> 6, lane = tid & 63;
    const int win  = blockIdx.y * 4 + wave;
    const int ls   = blockIdx.x * 64 + lane;
    const int gsig = sigBase + ls;

    float bands[7] = {0,0,0,0,0,0,0};
    const float2* xbase = (const float2*)x2c + (size_t)(25*win)*chunkW + ls;

    #pragma unroll
    for (int cc = 0; cc < 4; ++cc){
        const float* bp = basisP + cc*5500;
        float ar[11], ai[11];
        #pragma unroll
        for (int k = 0; k < 11; ++k){ ar[k] = 0.f; ai[k] = 0.f; }

        const float2* xp = xbase;
        #pragma unroll 2
        for (int step = 0; step < 125; ++step){
            float2 xv = *xp; xp += chunkW;
            const float* bs = bp + step*44;
            #pragma unroll
            for (int k = 0; k < 11; ++k){
                float4 b = *(const float4*)(bs + k*4);
                ar[k] = fmaf(xv.x, b.x, fmaf(xv.y, b.y, ar[k]));
                ai[k] = fmaf(xv.x, b.z, fmaf(xv.y, b.w, ai[k]));
            }
        }
        #pragma unroll
        for (int k = 0; k < 11; ++k){
            float p = fmaf(ar[k], ar[k], ai[k]*ai[k]) * (1.0f/250.0f);
            bands[band_of[1 + cc*11 + k]] += p;
        }
    }
    float* ob = psd + (size_t)gsig*252 + win*7;
    #pragma unroll
    for (int b = 0; b < 7; ++b) ob[b] = bands[b] * invcnt[b];
}

// ---------------------------------------------------------------------------
// Kernel N: per-signal z-norm of psd + DE -> feats. 1984 x 256 (wave=sig).
// ---------------------------------------------------------------------------
__global__ __launch_bounds__(256) void norm_kernel(
        const float* __restrict__ psd, float* __restrict__ feats)
{
    const int tid = threadIdx.x;
    const int wave = tid >> 6, lane = tid & 63;
    const int sig = blockIdx.x*4 + wave;

    float pv[4], dv[4];
    float s1p=0,s2p=0,s1d=0,s2d=0;
    #pragma unroll
    for (int i = 0; i < 4; ++i){
        int e = lane + i*64;
        if (e < 252){
            float p = psd[(size_t)sig*252 + e];
            float d = 0.5f * logf(17.079468445347134f*p + 1e-9f);
            pv[i] = p; dv[i] = d;
            s1p += p; s2p += p*p; s1d += d; s2d += d*d;
        }
    }
    #pragma unroll
    for (int off = 32; off > 0; off >>= 1){
        s1p += __shfl_down(s1p, off, 64); s2p += __shfl_down(s2p, off, 64);
        s1d += __shfl_down(s1d, off, 64); s2d += __shfl_down(s2d, off, 64);
    }
    s1p = __shfl(s1p, 0, 64); s2p = __shfl(s2p, 0, 64);
    s1d = __shfl(s1d, 0, 64); s2d = __shfl(s2d, 0, 64);
    float mp = s1p / 252.f;
    float sp = sqrtf(fmaxf((s2p - 252.f*mp*mp) / 251.f, 0.f)) + 1e-9f;
    float md = s1d / 252.f;
    float sd = sqrtf(fmaxf((s2d - 252.f*md*md) / 251.f, 0.f)) + 1e-9f;

    float* ob = feats + (size_t)sig * FDIM;
    #pragma unroll
    for (int i = 0; i < 4; ++i){
        int e = lane + i*64;
        if (e < 252){
            int w = e / 7, bi = e - w*7;
            ob[w*14 + bi]     = (pv[i] - mp) / sp;
            ob[w*14 + 7 + bi] = (dv[i] - md) / sd;
        }
    }
}

// ---------------------------------------------------------------------------
// Kernel FT: feats[b*62+c][k] -> featsT[b][k][64(c)]. grid (128,8) x 256.
// ---------------------------------------------------------------------------
__global__ __launch_bounds__(256) void featsT_kernel(
        const float* __restrict__ feats, float* __restrict__ featsT)
{
    __shared__ float t[62*64];
    const int tid = threadIdx.x;
    const int b   = blockIdx.x;
    const int k0  = blockIdx.y * 63;

    for (int idx = tid; idx < 62*63; idx += 256){
        int c = idx / 63, kk = idx - c*63;
        t[c*64 + kk] = feats[((size_t)b*62 + c)*FDIM + k0 + kk];
    }
    __syncthreads();
    for (int idx = tid; idx < 63*62; idx += 256){
        int kk = idx / 62, c = idx - kk*62;
        featsT[((size_t)b*504 + k0 + kk)*64 + c] = t[c*64 + kk];
    }
}

// ---------------------------------------------------------------------------
// Kernel DD v2: D^2[b][i][j]. grid (128,4) x 256. wave handles 4 i-rows;
// fj coalesced once per k serving 4 FMAs; fi wave-uniform.
// ---------------------------------------------------------------------------
__global__ __launch_bounds__(256) void dist_kernel(
        const float* __restrict__ featsT, float* __restrict__ Dsq)
{
    const int b    = blockIdx.x;
    const int wv   = threadIdx.x >> 6, lane = threadIdx.x & 63;
    const int i0   = (blockIdx.y * 4 + wv) * 4;      // 0..60
    const float* base = featsT + (size_t)b*504*64;

    float acc[4] = {0.f, 0.f, 0.f, 0.f};
    #pragma unroll 2
    for (int k = 0; k < 504; ++k){
        const float* rowp = base + (size_t)k*64;
        float fj = rowp[lane];
        #pragma unroll
        for (int ii = 0; ii < 4; ++ii){
            float d = rowp[i0 + ii] - fj;
            acc[ii] = fmaf(d, d, acc[ii]);
        }
    }
    if (lane < 62){
        #pragma unroll
        for (int ii = 0; ii < 4; ++ii){
            int i = i0 + ii;
            if (i < 62)
                Dsq[(size_t)b*3844 + i*62 + lane] = acc[ii];
        }
    }
}

// ---------------------------------------------------------------------------
// Kernel B2: Dm=sqrt(Dsq) -> FPS(5) -> temp assign -> atomics. 128 x 256.
// ---------------------------------------------------------------------------
__global__ __launch_bounds__(256) void fps_kernel(
        const float* __restrict__ Dsq, const float* __restrict__ pos_emb,
        float* __restrict__ gsums, float* __restrict__ gcnt)
{
    __shared__ float Dm[62*62];
    __shared__ float mdv[62];
    __shared__ float rsv[62];
    __shared__ int   seli[5];
    __shared__ float ccen[5][3];

    const int tid = threadIdx.x;
    const int b   = blockIdx.x;

    for (int e = tid; e < 3844; e += 256)
        Dm[e] = sqrtf(Dsq[(size_t)b*3844 + e]);
    __syncthreads();

    if (tid < 62){ float s = 0.f; for (int j = 0; j < 62; ++j) s += Dm[tid*62 + j]; rsv[tid] = s; }
    __syncthreads();
    if (tid == 0){
        int bi = 0; float bv = rsv[0];
        for (int i = 1; i < 62; ++i) if (rsv[i] > bv){ bv = rsv[i]; bi = i; }
        seli[0] = bi;
    }
    __syncthreads();
    if (tid < 62) mdv[tid] = Dm[seli[0]*62 + tid];
    __syncthreads();
    for (int it = 1; it < 5; ++it){
        if (tid == 0){
            int bi = 0; float bv = mdv[0];
            for (int i = 1; i < 62; ++i) if (mdv[i] > bv){ bv = mdv[i]; bi = i; }
            seli[it] = bi;
        }
        __syncthreads();
        if (tid < 62) mdv[tid] = fminf(mdv[tid], Dm[seli[it]*62 + tid]);
        __syncthreads();
    }
    if (tid < 5){
        int c0 = seli[tid];
        #pragma unroll
        for (int j = 0; j < 3; ++j) ccen[tid][j] = pos_emb[((size_t)b*62 + c0)*3 + j];
    }
    __syncthreads();
    if (tid < 62){
        float px = pos_emb[((size_t)b*62 + tid)*3 + 0];
        float py = pos_emb[((size_t)b*62 + tid)*3 + 1];
        float pz = pos_emb[((size_t)b*62 + tid)*3 + 2];
        int best = 0; float bd = 3.4e38f;
        #pragma unroll
        for (int t = 0; t < 5; ++t){
            float dx = px - ccen[t][0], dy = py - ccen[t][1], dz = pz - ccen[t][2];
            float d2 = dx*dx + dy*dy + dz*dz;
            if (d2 < bd){ bd = d2; best = t; }
        }
        atomicAdd(&gsums[best*3 + 0], px);
        atomicAdd(&gsums[best*3 + 1], py);
        atomicAdd(&gsums[best*3 + 2], pz);
        atomicAdd(&gcnt[best], 1.f);
    }
}

// ---------------------------------------------------------------------------
// Kernel C: pos FPS centers, center update, stable order + greedy assignment.
// ---------------------------------------------------------------------------
__global__ __launch_bounds__(64) void finalize_kernel(
        const float* __restrict__ pos_emb, const float* __restrict__ gsums,
        const float* __restrict__ gcnt, int* __restrict__ assign_out)
{
    __shared__ float P[62*3];
    __shared__ float Dp[62*62];
    __shared__ float rsv[62];
    __shared__ float mdv[62];
    __shared__ int   seli[5];
    __shared__ float cenS[5][3];
    __shared__ int   ordS[62][5];
    const int tid = threadIdx.x;

    if (tid < 62){
        #pragma unroll
        for (int j = 0; j < 3; ++j) P[tid*3 + j] = pos_emb[(size_t)tid*3 + j];
    }
    __syncthreads();
    if (tid < 62){
        float xi = P[tid*3], yi = P[tid*3+1], zi = P[tid*3+2];
        float s = 0.f;
        for (int j = 0; j < 62; ++j){
            float dx = xi - P[j*3], dy = yi - P[j*3+1], dz = zi - P[j*3+2];
            float d = sqrtf(dx*dx + dy*dy + dz*dz);
            Dp[tid*62 + j] = d; s += d;
        }
        rsv[tid] = s;
    }
    __syncthreads();
    if (tid == 0){
        int bi = 0; float bv = rsv[0];
        for (int i = 1; i < 62; ++i) if (rsv[i] > bv){ bv = rsv[i]; bi = i; }
        seli[0] = bi;
        for (int i = 0; i < 62; ++i) mdv[i] = Dp[bi*62 + i];
        for (int it = 1; it < 5; ++it){
            int fi = 0; float fv = mdv[0];
            for (int i = 1; i < 62; ++i) if (mdv[i] > fv){ fv = mdv[i]; fi = i; }
            seli[it] = fi;
            for (int i = 0; i < 62; ++i) mdv[i] = fminf(mdv[i], Dp[fi*62 + i]);
        }
        float cen[5][3], avg[5][3];
        for (int t = 0; t < 5; ++t)
            for (int j = 0; j < 3; ++j) cen[t][j] = P[seli[t]*3 + j];
        for (int t = 0; t < 5; ++t){
            float c = gcnt[t];
            for (int j = 0; j < 3; ++j)
                avg[t][j] = (c > 0.f) ? gsums[t*3 + j] / fmaxf(c, 1.f) : 0.f;
        }
        for (int i = 0; i < 5; ++i){
            int m = 0; float bv2 = 3.4e38f;
            for (int j = 0; j < 5; ++j){
                float dx = cen[i][0]-avg[j][0], dy = cen[i][1]-avg[j][1], dz = cen[i][2]-avg[j][2];
                float d2 = dx*dx + dy*dy + dz*dz;
                if (d2 < bv2){ bv2 = d2; m = j; }
            }
            for (int j = 0; j < 3; ++j) cenS[i][j] = 0.8f*cen[i][j] + 0.2f*avg[m][j];
        }
    }
    __syncthreads();
    if (tid < 62){
        float dd[5];
        #pragma unroll
        for (int t = 0; t < 5; ++t){
            float dx = P[tid*3]-cenS[t][0], dy = P[tid*3+1]-cenS[t][1], dz = P[tid*3+2]-cenS[t][2];
            dd[t] = sqrtf(dx*dx + dy*dy + dz*dz);
        }
        bool tk[5] = {false,false,false,false,false};
        #pragma unroll
        for (int s = 0; s < 5; ++s){
            int best = -1;
            #pragma unroll
            for (int t = 0; t < 5; ++t)
                if (!tk[t] && (best < 0 || dd[t] < dd[best])) best = t;
            tk[best] = true; ordS[tid][s] = best;
        }
    }
    __syncthreads();
    if (tid == 0){
        const int sizesA[5] = {13,13,12,12,12};
        int counts[5] = {0,0,0,0,0};
        for (int i = 0; i < 62; ++i){
            int cl = ordS[i][0];
            #pragma unroll
            for (int s = 0; s < 5; ++s){
                int t = ordS[i][s];
                if (counts[t] < sizesA[t]){ cl = t; break; }
            }
            counts[cl]++;
            assign_out[i] = cl;
        }
    }
}

// ---------------------------------------------------------------------------
// Kernel D: pf = relu(LN(feats @ W.T + b)) with TRANSPOSED weights.
// ---------------------------------------------------------------------------
__global__ __launch_bounds__(128) void proj_kernel(
        const float* __restrict__ feats, const float* __restrict__ projT,
        const float* __restrict__ proj_b, const float* __restrict__ lng,
        const float* __restrict__ lnb, float* __restrict__ pf)
{
    __shared__ float fs[8*FDIM];
    __shared__ float scr[4];
    const int tid = threadIdx.x;
    const int row0 = blockIdx.x * 8;

    for (int i = tid; i < 8*FDIM; i += 128)
        fs[i] = feats[(size_t)row0*FDIM + i];
    __syncthreads();

    float acc[8];
    const float bias = proj_b[tid];
    #pragma unroll
    for (int g = 0; g < 8; ++g) acc[g] = bias;

    #pragma unroll 4
    for (int k = 0; k < FDIM; ++k){
        float w = projT[k*128 + tid];
        #pragma unroll
        for (int g = 0; g < 8; ++g)
            acc[g] = fmaf(fs[g*FDIM + k], w, acc[g]);
    }
    const float gl = lng[tid], bl = lnb[tid];
    #pragma unroll
    for (int g = 0; g < 8; ++g){
        float s1 = acc[g], s2 = acc[g]*acc[g];
        bred2(s1, s2, scr, tid);
        float m = s1 * (1.f/128.f);
        float var = fmaxf(s2 * (1.f/128.f) - m*m, 0.f);
        float y = (acc[g] - m) / sqrtf(var + 1e-5f);
        y = y*gl + bl;
        pf[(size_t)(row0 + g)*DM + tid] = fmaxf(y, 0.f);
    }
}

// ---------------------------------------------------------------------------
// Kernel F: token pooling + 3-layer transformer, TRANSPOSED weights.
// ---------------------------------------------------------------------------
__global__ __launch_bounds__(128) void former_kernel(
        const float* __restrict__ pf, const int* __restrict__ assign,
        const float* __restrict__ pos_enc,
        const float* __restrict__ WqkvT, const float* __restrict__ bqkv,
        const float* __restrict__ WoT,   const float* __restrict__ bo,
        const float* __restrict__ W1T,   const float* __restrict__ b1,
        const float* __restrict__ W2T,   const float* __restrict__ b2,
        const float* __restrict__ ln1g, const float* __restrict__ ln1b,
        const float* __restrict__ ln2g, const float* __restrict__ ln2b,
        float* __restrict__ out)
{
    __shared__ float h[5*128];
    __shared__ float qkvL[5*384];
    __shared__ float attL[100];
    __shared__ float oL[5*128];
    __shared__ float hidL[5*256];
    __shared__ int   asg[62];
    __shared__ float scr[4];

    const int b = blockIdx.x;
    const int d = threadIdx.x;

    if (d < 62) asg[d] = assign[d];
    __syncthreads();

    {   // token pooling
        float a0=0,a1=0,a2=0,a3=0,a4=0;
        const float* pfb = pf + (size_t)b*62*DM + d;
        for (int c = 0; c < 62; ++c){
            float v = pfb[(size_t)c*DM];
            int a = asg[c];
            a0 += (a==0)?v:0.f; a1 += (a==1)?v:0.f; a2 += (a==2)?v:0.f;
            a3 += (a==3)?v:0.f; a4 += (a==4)?v:0.f;
        }
        h[0*128+d] = a0/13.f + pos_enc[0*128+d];
        h[1*128+d] = a1/13.f + pos_enc[1*128+d];
        h[2*128+d] = a2/12.f + pos_enc[2*128+d];
        h[3*128+d] = a3/12.f + pos_enc[3*128+d];
        h[4*128+d] = a4/12.f + pos_enc[4*128+d];
    }
    __syncthreads();

    for (int L = 0; L < 3; ++L){
        float acc[3][5];
        #pragma unroll
        for (int rr = 0; rr < 3; ++rr){
            float bb = bqkv[L*384 + rr*128 + d];
            #pragma unroll
            for (int t = 0; t < 5; ++t) acc[rr][t] = bb;
        }
        {
            const float* WT = WqkvT + (size_t)L*128*384;
            #pragma unroll 4
            for (int k = 0; k < 128; ++k){
                float h0 = h[0*128+k], h1 = h[1*128+k], h2 = h[2*128+k];
                float h3 = h[3*128+k], h4 = h[4*128+k];
                #pragma unroll
                for (int rr = 0; rr < 3; ++rr){
                    float w = WT[(size_t)k*384 + rr*128 + d];
                    acc[rr][0] = fmaf(h0, w, acc[rr][0]);
                    acc[rr][1] = fmaf(h1, w, acc[rr][1]);
                    acc[rr][2] = fmaf(h2, w, acc[rr][2]);
                    acc[rr][3] = fmaf(h3, w, acc[rr][3]);
                    acc[rr][4] = fmaf(h4, w, acc[rr][4]);
                }
            }
        }
        #pragma unroll
        for (int rr = 0; rr < 3; ++rr)
            #pragma unroll
            for (int t = 0; t < 5; ++t)
                qkvL[t*384 + rr*128 + d] = acc[rr][t];
        __syncthreads();

        if (d < 100){
            int hh = d/25, rem = d - hh*25, tq = rem/5, tk = rem - (rem/5)*5;
            const float* qq = &qkvL[tq*384 + hh*32];
            const float* kk = &qkvL[tk*384 + 128 + hh*32];
            float s = 0.f;
            #pragma unroll
            for (int j = 0; j < 32; ++j) s = fmaf(qq[j], kk[j], s);
            attL[d] = s * 0.17677669529663687f;
        }
        __syncthreads();
        if (d < 20){
            int hh = d/5, tq = d - hh*5;
            float* row = &attL[hh*25 + tq*5];
            float mx = row[0];
            #pragma unroll
            for (int j = 1; j < 5; ++j) mx = fmaxf(mx, row[j]);
            float sm = 0.f;
            #pragma unroll
            for (int j = 0; j < 5; ++j){ float e = expf(row[j]-mx); row[j] = e; sm += e; }
            float inv = 1.f/sm;
            #pragma unroll
            for (int j = 0; j < 5; ++j) row[j] *= inv;
        }
        __syncthreads();

        {
            int hh = d >> 5;
            #pragma unroll
            for (int t = 0; t < 5; ++t){
                float s = 0.f;
                #pragma unroll
                for (int tk = 0; tk < 5; ++tk)
                    s = fmaf(attL[hh*25 + t*5 + tk], qkvL[tk*384 + 256 + d], s);
                oL[t*128 + d] = s;
            }
        }
        __syncthreads();

        float val[5];
        {
            float bv = bo[L*128 + d];
            #pragma unroll
            for (int t = 0; t < 5; ++t) val[t] = bv;
            const float* WT = WoT + (size_t)L*128*128;
            #pragma unroll 4
            for (int k = 0; k < 128; ++k){
                float w = WT[(size_t)k*128 + d];
                #pragma unroll
                for (int t = 0; t < 5; ++t)
                    val[t] = fmaf(oL[t*128 + k], w, val[t]);
            }
            #pragma unroll
            for (int t = 0; t < 5; ++t) val[t] += h[t*128 + d];
        }
        {
            float ng = ln1g[L*128 + d], nb = ln1b[L*128 + d];
            #pragma unroll
            for (int t = 0; t < 5; ++t){
                float s1 = val[t], s2 = val[t]*val[t];
                bred2(s1, s2, scr, d);
                float m = s1*(1.f/128.f);
                float var = fmaxf(s2*(1.f/128.f) - m*m, 0.f);
                float y = (val[t] - m) / sqrtf(var + 1e-5f);
                h[t*128 + d] = y*ng + nb;
            }
        }
        __syncthreads();

        {
            float f1[2][5];
            #pragma unroll
            for (int rr = 0; rr < 2; ++rr){
                float bb = b1[L*256 + rr*128 + d];
                #pragma unroll
                for (int t = 0; t < 5; ++t) f1[rr][t] = bb;
            }
            const float* WT = W1T + (size_t)L*128*256;
            #pragma unroll 4
            for (int k = 0; k < 128; ++k){
                float h0 = h[0*128+k], h1 = h[1*128+k], h2 = h[2*128+k];
                float h3 = h[3*128+k], h4 = h[4*128+k];
                #pragma unroll
                for (int rr = 0; rr < 2; ++rr){
                    float w = WT[(size_t)k*256 + rr*128 + d];
                    f1[rr][0] = fmaf(h0, w, f1[rr][0]);
                    f1[rr][1] = fmaf(h1, w, f1[rr][1]);
                    f1[rr][2] = fmaf(h2, w, f1[rr][2]);
                    f1[rr][3] = fmaf(h3, w, f1[rr][3]);
                    f1[rr][4] = fmaf(h4, w, f1[rr][4]);
                }
            }
            #pragma unroll
            for (int rr = 0; rr < 2; ++rr)
                #pragma unroll
                for (int t = 0; t < 5; ++t)
                    hidL[t*256 + rr*128 + d] = fmaxf(f1[rr][t], 0.f);
        }
        __syncthreads();

        {
            float v2[5];
            float bv = b2[L*128 + d];
            #pragma unroll
            for (int t = 0; t < 5; ++t) v2[t] = bv;
            const float* WT = W2T + (size_t)L*256*128;
            #pragma unroll 4
            for (int k = 0; k < 256; ++k){
                float w = WT[(size_t)k*128 + d];
                #pragma unroll
                for (int t = 0; t < 5; ++t)
                    v2[t] = fmaf(hidL[t*256 + k], w, v2[t]);
            }
            #pragma unroll
            for (int t = 0; t < 5; ++t) v2[t] += h[t*128 + d];
            float ng = ln2g[L*128 + d], nb = ln2b[L*128 + d];
            #pragma unroll
            for (int t = 0; t < 5; ++t){
                float s1 = v2[t], s2 = v2[t]*v2[t];
                bred2(s1, s2, scr, d);
                float m = s1*(1.f/128.f);
                float var = fmaxf(s2*(1.f/128.f) - m*m, 0.f);
                float y = (v2[t] - m) / sqrtf(var + 1e-5f);
                h[t*128 + d] = y*ng + nb;
            }
        }
        __syncthreads();
    }

    #pragma unroll
    for (int t = 0; t < 5; ++t)
        out[((size_t)b*5 + t)*128 + d] = h[t*128 + d];
}

// ---------------------------------------------------------------------------
extern "C" void kernel_launch(void* const* d_in, const int* in_sizes, int n_in,
                              void* d_out, int out_size, void* d_ws, size_t ws_size,
                              hipStream_t stream)
{
    const float* x        = (const float*)d_in[0];
    const float* pos_emb  = (const float*)d_in[1];
    const float* proj_w   = (const float*)d_in[2];
    const float* proj_b   = (const float*)d_in[3];
    const float* proj_lng = (const float*)d_in[4];
    const float* proj_lnb = (const float*)d_in[5];
    const float* pos_enc  = (const float*)d_in[6];
    const float* Wqkv     = (const float*)d_in[7];
    const float* bqkv     = (const float*)d_in[8];
    const float* Wo       = (const float*)d_in[9];
    const float* bo       = (const float*)d_in[10];
    const float* W1       = (const float*)d_in[11];
    const float* b1       = (const float*)d_in[12];
    const float* W2       = (const float*)d_in[13];
    const float* b2       = (const float*)d_in[14];
    const float* ln1g     = (const float*)d_in[15];
    const float* ln1b     = (const float*)d_in[16];
    const float* ln2g     = (const float*)d_in[17];
    const float* ln2b     = (const float*)d_in[18];

    float* ws  = (float*)d_ws;
    float* out = (float*)d_out;

    const bool big = (ws_size >= (size_t)18351812 * 4 + 256);

    // common small-table sizes
    const size_t SZ_BASIS = 22000, SZ_PROJT = 64512, SZ_WQKVT = 147456,
                 SZ_WOT = 49152, SZ_W1T = 98304, SZ_W2T = 98304;

    size_t offTab = big ? 17872000 : 10100000;
    float* basisP = ws + offTab;
    float* projT  = basisP + SZ_BASIS;
    float* WqkvT  = projT + SZ_PROJT;
    float* WoT    = WqkvT + SZ_WQKVT;
    float* W1T    = WoT + SZ_WOT;
    float* W2T    = W1T + SZ_W1T;
    float* gsums  = W2T + SZ_W2T;
    float* gcnt   = gsums + 15;
    int*   assign = (int*)(gcnt + 5);

    float* x2c    = ws + 0;
    float* feats  = ws + 0;
    float* featsT = ws + 4000000;
    float* psd    = big ? (ws + 15872000) : (ws + 8100000);
    float* Dsq    = big ? (ws + 9200000)  : (ws + 8100000);
    float* pf     = big ? (ws + 8100000)  : (ws + 8600000);

    prep_kernel<<<1875, 256, 0, stream>>>(proj_w, Wqkv, Wo, W1, W2,
        basisP, projT, WqkvT, WoT, W1T, W2T, gsums);

    if (big){
        transpose_kernel<<<dim3(124,40), 256, 0, stream>>>(x, x2c, 0, N_SIG);
        feat_kernel<<<dim3(124,9), 256, 0, stream>>>(x2c, basisP, psd, 0, N_SIG);
    } else {
        transpose_kernel<<<dim3(62,40), 256, 0, stream>>>(x, x2c, 0, 3968);
        feat_kernel<<<dim3(62,9), 256, 0, stream>>>(x2c, basisP, psd, 0, 3968);
        transpose_kernel<<<dim3(62,40), 256, 0, stream>>>(x, x2c, 3968, 3968);
        feat_kernel<<<dim3(62,9), 256, 0, stream>>>(x2c, basisP, psd, 3968, 3968);
    }

    norm_kernel<<<1984, 256, 0, stream>>>(psd, feats);
    featsT_kernel<<<dim3(128,8), 256, 0, stream>>>(feats, featsT);
    dist_kernel<<<dim3(128,4), 256, 0, stream>>>(featsT, Dsq);
    fps_kernel<<<128, 256, 0, stream>>>(Dsq, pos_emb, gsums, gcnt);
    finalize_kernel<<<1, 64, 0, stream>>>(pos_emb, gsums, gcnt, assign);
    proj_kernel<<<992, 128, 0, stream>>>(feats, projT, proj_b, proj_lng, proj_lnb, pf);
    former_kernel<<<128, 128, 0, stream>>>(pf, assign, pos_enc,
        WqkvT, bqkv, WoT, bo, W1T, b1, W2T, b2, ln1g, ln1b, ln2g, ln2b, out);
}